// Round 1
// baseline (709.963 us; speedup 1.0000x reference)
//
#include <hip/hip_runtime.h>
#include <math.h>

// Shapes
#define NN 64
#define CC 64
#define TT 256
#define VV 25
#define DD 64
#define BN_EPS 1e-5f

// ws layout (in floats):
//  [0      : 4096)   pooled[n][c]
//  [4096   : 4352)   gate[n][4]
//  [4352   : 8448)   bfuse[n][d]
//  [8448   : 10048)  mask[v][c]  (= tanh(FM)+1)
//  [10048  : 11648)  stats1 (sum)   -- zeroed each launch
//  [11648  : 13248)  stats2 (sumsq) -- zeroed each launch
//  [13248  : 14848)  A[v*64+d]  (scale, out-feature indexed)
//  [14848  : 16448)  B[v*64+d]  (shift, out-feature indexed)
//  [16448  : 278592) Wt[n][d][c] (fused weight, transposed)
#define WS_POOLED 0
#define WS_GATE   4096
#define WS_BFUSE  4352
#define WS_MASK   8448
#define WS_S1     10048
#define WS_S2     11648
#define WS_A      13248
#define WS_B      14848
#define WS_WT     16448

// ---------------- K0: global average pool over (T,V) ----------------
__global__ __launch_bounds__(256) void k_pool(const float* __restrict__ x0,
                                              float* __restrict__ pooled) {
    __shared__ float red[256];
    const int bid = blockIdx.x;                // n*64 + c
    const float* p = x0 + (size_t)bid * (TT * VV);
    float s = 0.f;
    for (int k = threadIdx.x; k < TT * VV; k += 256) s += p[k];
    red[threadIdx.x] = s;
    __syncthreads();
    for (int off = 128; off > 0; off >>= 1) {
        if (threadIdx.x < off) red[threadIdx.x] += red[threadIdx.x + off];
        __syncthreads();
    }
    if (threadIdx.x == 0) pooled[bid] = red[0] * (1.f / (TT * VV));
}

// ---------------- K1: gate MLP + softmax, bfuse, mask ----------------
__global__ __launch_bounds__(256) void k_gate(const float* __restrict__ fc1_w,
                                              const float* __restrict__ fc1_b,
                                              const float* __restrict__ fc2_w,
                                              const float* __restrict__ fc2_b,
                                              const float* __restrict__ lin_b,
                                              const float* __restrict__ fmask,
                                              const int* __restrict__ epoch_p,
                                              float* ws) {
    const int tid = threadIdx.x;
    float* pooled = ws + WS_POOLED;
    float* gate   = ws + WS_GATE;
    float* bfuse  = ws + WS_BFUSE;
    float* mask   = ws + WS_MASK;

    if (tid < 64) {
        const int n = tid;
        const float* po = pooled + n * 64;
        float h[16];
        for (int q = 0; q < 16; q++) {
            float z = fc1_b[q];
            for (int j = 0; j < 64; j++) z = fmaf(fc1_w[q * 64 + j], po[j], z);
            h[q] = fmaxf(z, 0.f);
        }
        float lg[4];
        for (int k = 0; k < 4; k++) {
            float z = fc2_b[k];
            for (int q = 0; q < 16; q++) z = fmaf(fc2_w[k * 16 + q], h[q], z);
            lg[k] = z;
        }
        const int ep = epoch_p[0];
        const float tao = (ep < 60) ? (-(29.0f / 60.0f) * (float)ep + 30.0f) : 1.0f;
        float mx = -1e30f;
        for (int k = 0; k < 4; k++) { lg[k] /= tao; mx = fmaxf(mx, lg[k]); }
        float se = 0.f;
        for (int k = 0; k < 4; k++) { lg[k] = expf(lg[k] - mx); se += lg[k]; }
        const float inv = 1.f / se;
        for (int k = 0; k < 4; k++) gate[n * 4 + k] = lg[k] * inv;
    }
    __syncthreads();
    // bfuse[n][d] = sum_k Linear_bias[k][d] * gate[n][k]
    for (int f = tid; f < 4096; f += 256) {
        const int n = f >> 6, d = f & 63;
        float s = 0.f;
        for (int k = 0; k < 4; k++) s = fmaf(lin_b[k * 64 + d], gate[n * 4 + k], s);
        bfuse[f] = s;
    }
    // mask[v][c] = tanh(FM) + 1
    for (int f = tid; f < VV * CC; f += 256) mask[f] = tanhf(fmask[f]) + 1.0f;
}

// ---------------- K1b: fused weight, transposed Wt[n][d][c] ----------------
__global__ __launch_bounds__(256) void k_wfuse(const float* __restrict__ lw, float* ws) {
    __shared__ float tile[64 * 65];
    const float* gate = ws + WS_GATE;
    float* wt = ws + WS_WT;
    const int n = blockIdx.x;
    float g[4];
    for (int k = 0; k < 4; k++) g[k] = gate[n * 4 + k];
    // lw[k][c][d] flat = k*4096 + c*64 + d; read coalesced in d, transpose via LDS
    for (int f = threadIdx.x; f < 4096; f += 256) {
        const int c = f >> 6, d = f & 63;
        float v = g[0] * lw[f] + g[1] * lw[4096 + f] + g[2] * lw[8192 + f] + g[3] * lw[12288 + f];
        tile[d * 65 + c] = v;
    }
    __syncthreads();
    for (int f = threadIdx.x; f < 4096; f += 256) {
        const int d = f >> 6, c = f & 63;
        wt[n * 4096 + f] = tile[d * 65 + c];
    }
}

// ---------------- K3: finalize BN -> per-out-feature scale/shift ----------------
__global__ __launch_bounds__(256) void k_finalize(const float* __restrict__ gamma,
                                                  const float* __restrict__ beta,
                                                  float* ws) {
    const int f = blockIdx.x * 256 + threadIdx.x;   // out-feature v*64+d
    if (f >= VV * DD) return;
    const int v = f >> 6, d = f & 63;
    const int vi = (v - d + 175) % 25;              // source (unshifted) v index
    const int fin = vi * 64 + d;
    const float s1 = ws[WS_S1 + fin], s2 = ws[WS_S2 + fin];
    const float mean = s1 * (1.f / (NN * TT));
    float var = s2 * (1.f / (NN * TT)) - mean * mean;
    var = fmaxf(var, 0.f);
    const float rs = rsqrtf(var + BN_EPS);
    const float a = gamma[f] * rs;
    ws[WS_A + f] = a;
    ws[WS_B + f] = beta[f] - mean * a;
}

// ---------------- K2/K4: main per-sample GEMM ----------------
// PHASE 0: accumulate BN stats (atomics). PHASE 1: BN + shift-out + residual + relu -> out.
// Block: (tb = blockIdx.x in 0..63 -> 4 t's, n = blockIdx.y). 256 threads: d = tid&63, vg = tid>>6.
template <int PHASE>
__global__ __launch_bounds__(256) void k_main(const float* __restrict__ x0,
                                              const float* __restrict__ wt_all,
                                              const float* __restrict__ mask,
                                              const float* __restrict__ bfuse,
                                              float* __restrict__ stats1,
                                              float* __restrict__ stats2,
                                              const float* __restrict__ Abuf,
                                              const float* __restrict__ Bbuf,
                                              float* __restrict__ out) {
    __shared__ float W_lds[64 * 68];        // [d][c], padded
    __shared__ float xm[4 * 25 * 68];       // [t][v][c], padded; reused as out_lds[64][101] in phase 1
    const int n = blockIdx.y, tb = blockIdx.x;
    const int tid = threadIdx.x;
    const int d = tid & 63, vg = tid >> 6;

    // load fused weight tile (coalesced; 2-way LDS write conflict = free)
    const float* wt = wt_all + n * 4096;
    for (int f = tid; f < 4096; f += 256) W_lds[(f >> 6) * 68 + (f & 63)] = wt[f];

    // load x tile with shift-in gather + feature mask.
    // xm[t][i][j] = x0[n, j, tb*4+t, (i+j)%25] * mask[i][j]
    const float* xbase = x0 + (size_t)n * (CC * TT * VV) + tb * 100;
    for (int l = tid; l < 64 * 100; l += 256) {
        const int j = l / 100, r = l % 100;       // r = t*25 + p, contiguous in x0[n][j]
        const int t = r / 25, p = r % 25;
        const float v = xbase[j * (TT * VV) + r];
        const int i = (p - j + 175) % 25;          // dest v index
        xm[(t * 25 + i) * 68 + j] = v * mask[i * 64 + j];
    }
    const float bf = bfuse[n * 64 + d];
    __syncthreads();

    float acc[4][7];
#pragma unroll
    for (int t = 0; t < 4; t++)
#pragma unroll
        for (int s = 0; s < 7; s++) acc[t][s] = bf;

#pragma unroll 4
    for (int j4 = 0; j4 < 16; j4++) {
        const float4 wv = *(const float4*)&W_lds[d * 68 + j4 * 4];
#pragma unroll
        for (int t = 0; t < 4; t++) {
#pragma unroll
            for (int s = 0; s < 7; s++) {
                const int v = vg + 4 * s;
                if (v < 25) {
                    const float4 xv = *(const float4*)&xm[(t * 25 + v) * 68 + j4 * 4];
                    float a = acc[t][s];
                    a = fmaf(xv.x, wv.x, a);
                    a = fmaf(xv.y, wv.y, a);
                    a = fmaf(xv.z, wv.z, a);
                    a = fmaf(xv.w, wv.w, a);
                    acc[t][s] = a;
                }
            }
        }
    }

    if (PHASE == 0) {
#pragma unroll
        for (int s = 0; s < 7; s++) {
            const int v = vg + 4 * s;
            if (v >= 25) continue;
            float s1 = 0.f, s2 = 0.f;
#pragma unroll
            for (int t = 0; t < 4; t++) {
                const float y = acc[t][s];
                s1 += y;
                s2 = fmaf(y, y, s2);
            }
            atomicAdd(&stats1[v * 64 + d], s1);
            atomicAdd(&stats2[v * 64 + d], s2);
        }
    } else {
        __syncthreads();                      // done reading xm; reuse as out_lds
        float* out_lds = xm;                  // [64][101]
#pragma unroll
        for (int t = 0; t < 4; t++) {
#pragma unroll
            for (int s = 0; s < 7; s++) {
                const int v = vg + 4 * s;
                if (v >= 25) continue;
                const int vo = (v + d) % 25;  // shift-out dest v
                const int fo = vo * 64 + d;
                const float val = fmaf(Abuf[fo], acc[t][s], Bbuf[fo]);
                out_lds[d * 101 + t * 25 + vo] = val;
            }
        }
        __syncthreads();
        // write out[n,d,t,v] coalesced (100 contiguous floats per d), fuse residual+relu
        float* outp = out + (size_t)n * (DD * TT * VV) + tb * 100;
        const float* x0p = x0 + (size_t)n * (CC * TT * VV) + tb * 100;
        for (int l = tid; l < 64 * 100; l += 256) {
            const int dd = l / 100, r = l % 100;
            const float val = out_lds[dd * 101 + r] + x0p[dd * (TT * VV) + r];
            outp[dd * (TT * VV) + r] = fmaxf(val, 0.f);
        }
    }
}

extern "C" void kernel_launch(void* const* d_in, const int* in_sizes, int n_in,
                              void* d_out, int out_size, void* d_ws, size_t ws_size,
                              hipStream_t stream) {
    const float* x0    = (const float*)d_in[0];
    const float* fc1_w = (const float*)d_in[1];
    const float* fc1_b = (const float*)d_in[2];
    const float* fc2_w = (const float*)d_in[3];
    const float* fc2_b = (const float*)d_in[4];
    const float* lw    = (const float*)d_in[5];
    const float* lb    = (const float*)d_in[6];
    const float* fmask = (const float*)d_in[7];
    const float* gamma = (const float*)d_in[8];
    const float* beta  = (const float*)d_in[9];
    const int* epoch   = (const int*)d_in[12];
    float* ws  = (float*)d_ws;
    float* out = (float*)d_out;

    k_pool<<<NN * CC, 256, 0, stream>>>(x0, ws + WS_POOLED);
    k_gate<<<1, 256, 0, stream>>>(fc1_w, fc1_b, fc2_w, fc2_b, lb, fmask, epoch, ws);
    k_wfuse<<<NN, 256, 0, stream>>>(lw, ws);
    hipMemsetAsync((char*)d_ws + WS_S1 * sizeof(float), 0, 3200 * sizeof(float), stream);

    dim3 g2(64, 64);
    k_main<0><<<g2, 256, 0, stream>>>(x0, ws + WS_WT, ws + WS_MASK, ws + WS_BFUSE,
                                      ws + WS_S1, ws + WS_S2, ws + WS_A, ws + WS_B, out);
    k_finalize<<<7, 256, 0, stream>>>(gamma, beta, ws);
    k_main<1><<<g2, 256, 0, stream>>>(x0, ws + WS_WT, ws + WS_MASK, ws + WS_BFUSE,
                                      ws + WS_S1, ws + WS_S2, ws + WS_A, ws + WS_B, out);
}

// Round 2
// 476.662 us; speedup vs baseline: 1.4894x; 1.4894x over previous
//
#include <hip/hip_runtime.h>
#include <hip/hip_bf16.h>
#include <math.h>

// Shapes
#define NN 64
#define CC 64
#define TT 256
#define VV 25
#define DD 64
#define BN_EPS 1e-5f

typedef short bf16x8 __attribute__((ext_vector_type(8)));
typedef float f32x4 __attribute__((ext_vector_type(4)));

// ws layout (in floats):
#define WS_POOLED 0            // [64][64]
#define WS_GATE   4096         // [64][4]
#define WS_BFUSE  4352         // [64][64]
#define WS_MASK   8448         // [25][64]
#define WS_A      10048        // [1600] out-feature scale
#define WS_B      11648        // [1600] out-feature shift
#define WS_PART1  13248        // [64][1600] per-n partial sum   (memset 0)
#define WS_PART2  115648       // [64][1600] per-n partial sumsq (memset 0)
#define WS_WTB    218048       // ushort[64][64][64]  fused W transposed [n][d][c], bf16

// ---------------- K0: global average pool over (T,V) ----------------
__global__ __launch_bounds__(256) void k_pool(const float* __restrict__ x0,
                                              float* __restrict__ pooled) {
    __shared__ float red[256];
    const int bid = blockIdx.x;                // n*64 + c
    const float4* p = (const float4*)(x0 + (size_t)bid * (TT * VV));
    float s = 0.f;
    for (int k = threadIdx.x; k < (TT * VV) / 4; k += 256) {
        float4 v = p[k];
        s += v.x + v.y + v.z + v.w;
    }
    red[threadIdx.x] = s;
    __syncthreads();
    for (int off = 128; off > 0; off >>= 1) {
        if (threadIdx.x < off) red[threadIdx.x] += red[threadIdx.x + off];
        __syncthreads();
    }
    if (threadIdx.x == 0) pooled[bid] = red[0] * (1.f / (TT * VV));
}

// ---------------- K1: gate MLP + softmax, bfuse, mask ----------------
__global__ __launch_bounds__(256) void k_gate(const float* __restrict__ fc1_w,
                                              const float* __restrict__ fc1_b,
                                              const float* __restrict__ fc2_w,
                                              const float* __restrict__ fc2_b,
                                              const float* __restrict__ lin_b,
                                              const float* __restrict__ fmask,
                                              const int* __restrict__ epoch_p,
                                              float* ws) {
    const int tid = threadIdx.x;
    float* pooled = ws + WS_POOLED;
    float* gate   = ws + WS_GATE;
    float* bfuse  = ws + WS_BFUSE;
    float* mask   = ws + WS_MASK;

    if (tid < 64) {
        const int n = tid;
        const float* po = pooled + n * 64;
        float h[16];
        for (int q = 0; q < 16; q++) {
            float z = fc1_b[q];
            for (int j = 0; j < 64; j++) z = fmaf(fc1_w[q * 64 + j], po[j], z);
            h[q] = fmaxf(z, 0.f);
        }
        float lg[4];
        for (int k = 0; k < 4; k++) {
            float z = fc2_b[k];
            for (int q = 0; q < 16; q++) z = fmaf(fc2_w[k * 16 + q], h[q], z);
            lg[k] = z;
        }
        const int ep = epoch_p[0];
        const float tao = (ep < 60) ? (-(29.0f / 60.0f) * (float)ep + 30.0f) : 1.0f;
        float mx = -1e30f;
        for (int k = 0; k < 4; k++) { lg[k] /= tao; mx = fmaxf(mx, lg[k]); }
        float se = 0.f;
        for (int k = 0; k < 4; k++) { lg[k] = expf(lg[k] - mx); se += lg[k]; }
        const float inv = 1.f / se;
        for (int k = 0; k < 4; k++) gate[n * 4 + k] = lg[k] * inv;
    }
    __syncthreads();
    for (int f = tid; f < 4096; f += 256) {
        const int n = f >> 6, d = f & 63;
        float s = 0.f;
        for (int k = 0; k < 4; k++) s = fmaf(lin_b[k * 64 + d], gate[n * 4 + k], s);
        bfuse[f] = s;
    }
    for (int f = tid; f < VV * CC; f += 256) mask[f] = tanhf(fmask[f]) + 1.0f;
}

// ---------------- K1b: fused weight, transposed, bf16: Wtb[n][d][c] ----------------
__global__ __launch_bounds__(256) void k_wfuse(const float* __restrict__ lw, float* ws) {
    __shared__ float tile[64 * 65];
    const float* gate = ws + WS_GATE;
    unsigned short* wtb = (unsigned short*)(ws + WS_WTB);
    const int n = blockIdx.x;
    float g[4];
    for (int k = 0; k < 4; k++) g[k] = gate[n * 4 + k];
    for (int f = threadIdx.x; f < 4096; f += 256) {
        const int c = f >> 6, d = f & 63;
        float v = g[0] * lw[f] + g[1] * lw[4096 + f] + g[2] * lw[8192 + f] + g[3] * lw[12288 + f];
        tile[d * 65 + c] = v;
    }
    __syncthreads();
    for (int f = threadIdx.x; f < 4096; f += 256) {
        const int d = f >> 6, c = f & 63;
        __hip_bfloat16 h = __float2bfloat16(tile[d * 65 + c]);
        wtb[n * 4096 + f] = *(unsigned short*)&h;
    }
}

// ---------------- K3: finalize BN -> per-out-feature scale/shift ----------------
__global__ __launch_bounds__(256) void k_finalize(const float* __restrict__ gamma,
                                                  const float* __restrict__ beta,
                                                  float* ws) {
    const int f = blockIdx.x * 256 + threadIdx.x;   // out-feature v*64+d
    if (f >= VV * DD) return;
    const int v = f >> 6, d = f & 63;
    const int vi = (v - d + 175) % 25;              // source (unshifted) v index
    const int fin = vi * 64 + d;
    const float* part1 = ws + WS_PART1;
    const float* part2 = ws + WS_PART2;
    float s1 = 0.f, s2 = 0.f;
    for (int n = 0; n < 64; n++) {
        s1 += part1[n * 1600 + fin];
        s2 += part2[n * 1600 + fin];
    }
    const float mean = s1 * (1.f / (NN * TT));
    float var = s2 * (1.f / (NN * TT)) - mean * mean;
    var = fmaxf(var, 0.f);
    const float rs = rsqrtf(var + BN_EPS);
    const float a = gamma[f] * rs;
    ws[WS_A + f] = a;
    ws[WS_B + f] = beta[f] - mean * a;
}

// ---------------- K2/K4: main per-sample GEMM via bf16 MFMA ----------------
// Block (tb = blockIdx.x: 4 t's, n = blockIdx.y), 256 threads = 4 waves.
// A = xm [112(pad)][64] bf16 (rows = t*25+v shifted-in, cols = c)
// B = Wt [64][64] bf16 (rows = d, cols = c)  ->  y[row][d] = sum_c A*B
// Wave w owns N-tile w (d = w*16..w*16+15), loops 7 M-tiles, K in 2 steps of 32.
template <int PHASE>
__global__ __launch_bounds__(256) void k_main(const float* __restrict__ x0,
                                              const unsigned short* __restrict__ wtb,
                                              const float* __restrict__ mask,
                                              const float* __restrict__ bfuse,
                                              float* __restrict__ part1,
                                              float* __restrict__ part2,
                                              const float* __restrict__ Abuf,
                                              const float* __restrict__ Bbuf,
                                              float* __restrict__ out) {
    __shared__ __align__(16) char pool[26112];
    unsigned short (*Xm)[72] = (unsigned short(*)[72])pool;            // [112][72] bf16, 16128 B
    unsigned short (*Wl)[72] = (unsigned short(*)[72])(pool + 16128);  // [64][72] bf16, 9216 B

    const int n = blockIdx.y, tb = blockIdx.x;
    const int tid = threadIdx.x;
    const int wv = tid >> 6;            // wave = N-tile
    const int lane = tid & 63;
    const int lrow = lane & 15, lgrp = lane >> 4;
    const int dcol = wv * 16 + lrow;

    // ---- stage W (bf16, coalesced uint4) ----
    {
        const uint4* wsrc = (const uint4*)(wtb + n * 4096);
        for (int it = tid; it < 512; it += 256) {
            uint4 u = wsrc[it];
            const int f8 = it * 8;
            *(uint4*)&Wl[f8 >> 6][f8 & 63] = u;
        }
    }
    // ---- stage X with shift-in gather + mask, f32 -> bf16 ----
    // Xm[t*25+i][j] = bf16( x0[n, j, tb*4+t, (i+j)%25] * mask[i][j] )
    const float* xbase = x0 + (size_t)n * (CC * TT * VV) + tb * 100;
    for (int l = tid; l < 6400; l += 256) {
        const int j = l / 100, r = l - j * 100;     // r = t*25 + p
        const int t = r / 25, p = r - t * 25;
        const float xv = xbase[j * (TT * VV) + r];
        const int i = (p - j + 175) % 25;
        __hip_bfloat16 h = __float2bfloat16(xv * mask[i * 64 + j]);
        Xm[t * 25 + i][j] = *(unsigned short*)&h;
    }
    const float bfv = bfuse[n * 64 + dcol];
    __syncthreads();

    // ---- MFMA ----
    bf16x8 b0 = *(const bf16x8*)&Wl[dcol][8 * lgrp];
    bf16x8 b1 = *(const bf16x8*)&Wl[dcol][32 + 8 * lgrp];
    f32x4 acc[7];
#pragma unroll
    for (int m = 0; m < 7; m++) {
        f32x4 a = {bfv, bfv, bfv, bfv};
        bf16x8 a0 = *(const bf16x8*)&Xm[m * 16 + lrow][8 * lgrp];
        bf16x8 a1 = *(const bf16x8*)&Xm[m * 16 + lrow][32 + 8 * lgrp];
        a = __builtin_amdgcn_mfma_f32_16x16x32_bf16(a0, b0, a, 0, 0, 0);
        a = __builtin_amdgcn_mfma_f32_16x16x32_bf16(a1, b1, a, 0, 0, 0);
        acc[m] = a;
    }
    __syncthreads();   // LDS tiles dead; reuse pool

    if (PHASE == 0) {
        // zero LDS stats, reduce fragments, one global atomic pair per (v,d) into part[n]
        float* s1l = (float*)pool;          // [25][64]
        float* s2l = s1l + 1600;
        for (int f = tid; f < 3200; f += 256) s1l[f] = 0.f;
        __syncthreads();
#pragma unroll
        for (int m = 0; m < 7; m++) {
#pragma unroll
            for (int r = 0; r < 4; r++) {
                const int row = m * 16 + 4 * lgrp + r;
                if (row < 100) {
                    const float y = acc[m][r];
                    const int t = row / 25;
                    const int off = (row - t * 25) * 64 + dcol;
                    __hip_atomic_fetch_add(&s1l[off], y, __ATOMIC_RELAXED, __HIP_MEMORY_SCOPE_WORKGROUP);
                    __hip_atomic_fetch_add(&s2l[off], y * y, __ATOMIC_RELAXED, __HIP_MEMORY_SCOPE_WORKGROUP);
                }
            }
        }
        __syncthreads();
        for (int f = tid; f < 1600; f += 256) {
            atomicAdd(&part1[n * 1600 + f], s1l[f]);
            atomicAdd(&part2[n * 1600 + f], s2l[f]);
        }
    } else {
        // BN + shift-out into out_lds[d][t*25+vo], then coalesced write + residual + relu
        float* outl = (float*)pool;         // [64][101]
#pragma unroll
        for (int m = 0; m < 7; m++) {
#pragma unroll
            for (int r = 0; r < 4; r++) {
                const int row = m * 16 + 4 * lgrp + r;
                if (row < 100) {
                    const int t = row / 25, v = row - t * 25;
                    const int vo = (v + dcol) % 25;
                    const int fo = vo * 64 + dcol;
                    outl[dcol * 101 + t * 25 + vo] = fmaf(Abuf[fo], acc[m][r], Bbuf[fo]);
                }
            }
        }
        __syncthreads();
        float* outp = out + (size_t)n * (DD * TT * VV) + tb * 100;
        const float* x0p = x0 + (size_t)n * (CC * TT * VV) + tb * 100;
        for (int l = tid; l < 6400; l += 256) {
            const int dd = l / 100, r = l - dd * 100;
            const float val = outl[dd * 101 + r] + x0p[dd * (TT * VV) + r];
            outp[dd * (TT * VV) + r] = fmaxf(val, 0.f);
        }
    }
}

extern "C" void kernel_launch(void* const* d_in, const int* in_sizes, int n_in,
                              void* d_out, int out_size, void* d_ws, size_t ws_size,
                              hipStream_t stream) {
    const float* x0    = (const float*)d_in[0];
    const float* fc1_w = (const float*)d_in[1];
    const float* fc1_b = (const float*)d_in[2];
    const float* fc2_w = (const float*)d_in[3];
    const float* fc2_b = (const float*)d_in[4];
    const float* lw    = (const float*)d_in[5];
    const float* lb    = (const float*)d_in[6];
    const float* fmask = (const float*)d_in[7];
    const float* gamma = (const float*)d_in[8];
    const float* beta  = (const float*)d_in[9];
    const int* epoch   = (const int*)d_in[12];
    float* ws  = (float*)d_ws;
    float* out = (float*)d_out;
    const unsigned short* wtb = (const unsigned short*)(ws + WS_WTB);

    k_pool<<<NN * CC, 256, 0, stream>>>(x0, ws + WS_POOLED);
    k_gate<<<1, 256, 0, stream>>>(fc1_w, fc1_b, fc2_w, fc2_b, lb, fmask, epoch, ws);
    k_wfuse<<<NN, 256, 0, stream>>>(lw, ws);
    hipMemsetAsync((char*)d_ws + WS_PART1 * sizeof(float), 0, 204800 * sizeof(float), stream);

    dim3 g2(64, 64);
    k_main<0><<<g2, 256, 0, stream>>>(x0, wtb, ws + WS_MASK, ws + WS_BFUSE,
                                      ws + WS_PART1, ws + WS_PART2, ws + WS_A, ws + WS_B, out);
    k_finalize<<<7, 256, 0, stream>>>(gamma, beta, ws);
    k_main<1><<<g2, 256, 0, stream>>>(x0, wtb, ws + WS_MASK, ws + WS_BFUSE,
                                      ws + WS_PART1, ws + WS_PART2, ws + WS_A, ws + WS_B, out);
}

// Round 3
// 230.441 us; speedup vs baseline: 3.0809x; 2.0685x over previous
//
#include <hip/hip_runtime.h>
#include <hip/hip_bf16.h>
#include <math.h>

// Shapes
#define NN 64
#define CC 64
#define TT 256
#define VV 25
#define DD 64
#define BN_EPS 1e-5f

typedef short bf16x8 __attribute__((ext_vector_type(8)));
typedef float f32x4 __attribute__((ext_vector_type(4)));

// ws layout (floats)
#define WS_POOLED 0            // [64][64]
#define WS_GATE   4096         // [64][4]
#define WS_BFUSE  4352         // [64][64]
#define WS_MASK   8448         // [25][64] f32
#define WS_A      10048        // [1600]
#define WS_B      11648        // [1600]
#define WS_S1     13248        // [8][1600] replicas (memset 0)
#define WS_S2     26048        // [8][1600]
#define WS_WTB    38848        // ushort[64][64][64] fused W^T bf16

// LDS pool layout (bytes)
#define OFF_W     0            // ushort[64][72]            9216
#define OFF_MASK  9216         // float [25][65]            6500
#define OFF_A     15728        // float [25][66] | p0 stats1
#define OFF_B     22336        // float [25][66] | p0 stats2
#define OFF_XM    28944        // ushort[112][72] | float outl[64][100]
#define LDS_BYTES 54560

static __device__ __forceinline__ unsigned short f2bf(float x) {
    __hip_bfloat16 h = __float2bfloat16(x);
    return *(unsigned short*)&h;
}

// ---------------- K0: global average pool over (T,V) ----------------
__global__ __launch_bounds__(256) void k_pool(const float* __restrict__ x0,
                                              float* __restrict__ pooled) {
    __shared__ float red[256];
    const int bid = blockIdx.x;                // n*64 + c
    const float4* p = (const float4*)(x0 + (size_t)bid * (TT * VV));
    float s = 0.f;
    for (int k = threadIdx.x; k < (TT * VV) / 4; k += 256) {
        float4 v = p[k];
        s += v.x + v.y + v.z + v.w;
    }
    red[threadIdx.x] = s;
    __syncthreads();
    for (int off = 128; off > 0; off >>= 1) {
        if (threadIdx.x < off) red[threadIdx.x] += red[threadIdx.x + off];
        __syncthreads();
    }
    if (threadIdx.x == 0) pooled[bid] = red[0] * (1.f / (TT * VV));
}

// ---------------- K1: gate MLP + softmax, bfuse, mask ----------------
__global__ __launch_bounds__(256) void k_gate(const float* __restrict__ fc1_w,
                                              const float* __restrict__ fc1_b,
                                              const float* __restrict__ fc2_w,
                                              const float* __restrict__ fc2_b,
                                              const float* __restrict__ lin_b,
                                              const float* __restrict__ fmask,
                                              const int* __restrict__ epoch_p,
                                              float* ws) {
    const int tid = threadIdx.x;
    float* pooled = ws + WS_POOLED;
    float* gate   = ws + WS_GATE;
    float* bfuse  = ws + WS_BFUSE;
    float* mask   = ws + WS_MASK;

    if (tid < 64) {
        const int n = tid;
        const float* po = pooled + n * 64;
        float h[16];
        for (int q = 0; q < 16; q++) {
            float z = fc1_b[q];
            for (int j = 0; j < 64; j++) z = fmaf(fc1_w[q * 64 + j], po[j], z);
            h[q] = fmaxf(z, 0.f);
        }
        float lg[4];
        for (int k = 0; k < 4; k++) {
            float z = fc2_b[k];
            for (int q = 0; q < 16; q++) z = fmaf(fc2_w[k * 16 + q], h[q], z);
            lg[k] = z;
        }
        const int ep = epoch_p[0];
        const float tao = (ep < 60) ? (-(29.0f / 60.0f) * (float)ep + 30.0f) : 1.0f;
        float mx = -1e30f;
        for (int k = 0; k < 4; k++) { lg[k] /= tao; mx = fmaxf(mx, lg[k]); }
        float se = 0.f;
        for (int k = 0; k < 4; k++) { lg[k] = expf(lg[k] - mx); se += lg[k]; }
        const float inv = 1.f / se;
        for (int k = 0; k < 4; k++) gate[n * 4 + k] = lg[k] * inv;
    }
    __syncthreads();
    for (int f = tid; f < 4096; f += 256) {
        const int n = f >> 6, d = f & 63;
        float s = 0.f;
        for (int k = 0; k < 4; k++) s = fmaf(lin_b[k * 64 + d], gate[n * 4 + k], s);
        bfuse[f] = s;
    }
    for (int f = tid; f < VV * CC; f += 256) mask[f] = tanhf(fmask[f]) + 1.0f;
}

// ---------------- K1b: fused weight, transposed, bf16: Wtb[n][d][c] ----------------
__global__ __launch_bounds__(256) void k_wfuse(const float* __restrict__ lw, float* ws) {
    __shared__ float tile[64 * 65];
    const float* gate = ws + WS_GATE;
    unsigned short* wtb = (unsigned short*)(ws + WS_WTB);
    const int n = blockIdx.x;
    float g[4];
    for (int k = 0; k < 4; k++) g[k] = gate[n * 4 + k];
    for (int f = threadIdx.x; f < 4096; f += 256) {
        const int c = f >> 6, d = f & 63;
        float v = g[0] * lw[f] + g[1] * lw[4096 + f] + g[2] * lw[8192 + f] + g[3] * lw[12288 + f];
        tile[d * 65 + c] = v;
    }
    __syncthreads();
    for (int f = threadIdx.x; f < 4096; f += 256) {
        const int d = f >> 6, c = f & 63;
        wtb[n * 4096 + f] = f2bf(tile[d * 65 + c]);
    }
}

// ---------------- K3: finalize BN -> per-out-feature scale/shift ----------------
__global__ __launch_bounds__(256) void k_finalize(const float* __restrict__ gamma,
                                                  const float* __restrict__ beta,
                                                  float* ws) {
    const int f = blockIdx.x * 256 + threadIdx.x;   // out-feature v*64+d
    if (f >= VV * DD) return;
    const int v = f >> 6, d = f & 63;
    const int vi = (v - d + 175) % 25;              // source (unshifted) v index
    const int fin = vi * 64 + d;
    float s1 = 0.f, s2 = 0.f;
    for (int rep = 0; rep < 8; rep++) {
        s1 += ws[WS_S1 + rep * 1600 + fin];
        s2 += ws[WS_S2 + rep * 1600 + fin];
    }
    const float mean = s1 * (1.f / (NN * TT));
    float var = s2 * (1.f / (NN * TT)) - mean * mean;
    var = fmaxf(var, 0.f);
    const float rs = rsqrtf(var + BN_EPS);
    const float a = gamma[f] * rs;
    ws[WS_A + f] = a;
    ws[WS_B + f] = beta[f] - mean * a;
}

// ---------------- K2/K4: main per-sample GEMM via bf16 MFMA ----------------
// Grid (16 tb, 64 n). Block covers 16 t's in 4 chunks of 4.
template <int PHASE>
__global__ __launch_bounds__(256) void k_main(const float* __restrict__ x0,
                                              const unsigned short* __restrict__ wtb,
                                              const float* __restrict__ ws,
                                              float* __restrict__ wsmut,
                                              float* __restrict__ out) {
    __shared__ __align__(16) char pool[LDS_BYTES];
    unsigned short (*Wl)[72] = (unsigned short(*)[72])(pool + OFF_W);
    float* maskL = (float*)(pool + OFF_MASK);            // [i*65+j]
    float* Al = (float*)(pool + OFF_A);                  // phase1 A | phase0 stats1, pitch 66
    float* Bl = (float*)(pool + OFF_B);                  // phase1 B | phase0 stats2, pitch 66
    unsigned short (*Xm)[72] = (unsigned short(*)[72])(pool + OFF_XM);
    float* outl = (float*)(pool + OFF_XM);               // [64][100], aliases Xm

    const int n = blockIdx.y, tb = blockIdx.x;
    const int tid = threadIdx.x;
    const int wv = tid >> 6, lane = tid & 63;
    const int lrow = lane & 15, lgrp = lane >> 4;
    const int dcol = wv * 16 + lrow;

    // ---- one-time staging ----
    {
        const uint4* wsrc = (const uint4*)(wtb + n * 4096);
        for (int it = tid; it < 512; it += 256) {
            uint4 u = wsrc[it];
            const int f8 = it * 8;
            *(uint4*)&Wl[f8 >> 6][f8 & 63] = u;
        }
        const float* maskf = ws + WS_MASK;
        for (int f = tid; f < 1600; f += 256) {
            const int i = f >> 6, j = f & 63;
            maskL[i * 65 + j] = maskf[f];
        }
        if (PHASE == 0) {
            float* z = (float*)(pool + OFF_A);
            for (int f = tid; f < 3304; f += 256) z[f] = 0.f;
        } else {
            const float* Ag = ws + WS_A;
            const float* Bg = ws + WS_B;
            for (int f = tid; f < 1600; f += 256) {
                const int v = f >> 6, d = f & 63;
                Al[v * 66 + d] = Ag[f];
                Bl[v * 66 + d] = Bg[f];
            }
        }
    }
    const float bfv = ws[WS_BFUSE + n * 64 + dcol];
    __syncthreads();

    const bf16x8 b0 = *(const bf16x8*)&Wl[dcol][8 * lgrp];
    const bf16x8 b1 = *(const bf16x8*)&Wl[dcol][32 + 8 * lgrp];

    float s1r[7][4], s2r[7][4];
    if (PHASE == 0) {
#pragma unroll
        for (int m = 0; m < 7; m++)
#pragma unroll
            for (int r = 0; r < 4; r++) { s1r[m][r] = 0.f; s2r[m][r] = 0.f; }
    }

    const size_t nbase = (size_t)n * (CC * TT * VV);

    for (int ck = 0; ck < 4; ck++) {
        const int gcol0 = tb * 400 + ck * 100;
        // ---- stage X chunk: float4 loads, shift-in gather + mask, f32->bf16 ----
        for (int l4 = tid; l4 < 1600; l4 += 256) {
            const int j = l4 / 25, q = l4 - j * 25;
            const float4 xv = *(const float4*)(x0 + nbase + j * 6400 + gcol0 + q * 4);
            int jm = j; if (jm >= 50) jm -= 50; else if (jm >= 25) jm -= 25;
            const int r0 = q * 4;
            const float xe[4] = {xv.x, xv.y, xv.z, xv.w};
#pragma unroll
            for (int e = 0; e < 4; e++) {
                const int r = r0 + e;
                const int trel = (r >= 75) ? 3 : (r >= 50) ? 2 : (r >= 25) ? 1 : 0;
                const int p = r - trel * 25;
                int i = p - jm + 25; if (i >= 25) i -= 25;
                Xm[trel * 25 + i][j] = f2bf(xe[e] * maskL[i * 65 + j]);
            }
        }
        __syncthreads();
        // ---- MFMA ----
        f32x4 acc[7];
#pragma unroll
        for (int m = 0; m < 7; m++) {
            f32x4 a = {bfv, bfv, bfv, bfv};
            const bf16x8 a0 = *(const bf16x8*)&Xm[m * 16 + lrow][8 * lgrp];
            const bf16x8 a1 = *(const bf16x8*)&Xm[m * 16 + lrow][32 + 8 * lgrp];
            a = __builtin_amdgcn_mfma_f32_16x16x32_bf16(a0, b0, a, 0, 0, 0);
            a = __builtin_amdgcn_mfma_f32_16x16x32_bf16(a1, b1, a, 0, 0, 0);
            acc[m] = a;
        }
        __syncthreads();       // Xm reads done; region may be rewritten

        if (PHASE == 0) {
#pragma unroll
            for (int m = 0; m < 7; m++) {
#pragma unroll
                for (int r = 0; r < 4; r++) {
                    const int row = m * 16 + 4 * lgrp + r;
                    if (row < 100) {
                        const float y = acc[m][r];
                        s1r[m][r] += y;
                        s2r[m][r] = fmaf(y, y, s2r[m][r]);
                    }
                }
            }
            // next chunk staging protected by the barrier above
        } else {
            // BN + shift-out into outl[d][trel*25+vo]
#pragma unroll
            for (int m = 0; m < 7; m++) {
#pragma unroll
                for (int r = 0; r < 4; r++) {
                    const int row = m * 16 + 4 * lgrp + r;
                    if (row < 100) {
                        const int trel = (row >= 75) ? 3 : (row >= 50) ? 2 : (row >= 25) ? 1 : 0;
                        const int v = row - trel * 25;
                        int vo = v + dcol;
                        if (vo >= 75) vo -= 75; else if (vo >= 50) vo -= 50; else if (vo >= 25) vo -= 25;
                        outl[dcol * 100 + trel * 25 + vo] =
                            fmaf(Al[vo * 66 + dcol], acc[m][r], Bl[vo * 66 + dcol]);
                    }
                }
            }
            __syncthreads();
            // coalesced float4 flush + residual + relu
            for (int l4 = tid; l4 < 1600; l4 += 256) {
                const int dd = l4 / 25, q = l4 - dd * 25;
                const float4 vv = *(const float4*)&outl[dd * 100 + q * 4];
                const float4 xr = *(const float4*)(x0 + nbase + dd * 6400 + gcol0 + q * 4);
                float4 o;
                o.x = fmaxf(vv.x + xr.x, 0.f);
                o.y = fmaxf(vv.y + xr.y, 0.f);
                o.z = fmaxf(vv.z + xr.z, 0.f);
                o.w = fmaxf(vv.w + xr.w, 0.f);
                *(float4*)(out + nbase + dd * 6400 + gcol0 + q * 4) = o;
            }
            __syncthreads();   // before next chunk overwrites outl
        }
    }

    if (PHASE == 0) {
        // LDS reduce (stats pitch 66), then one global atomic per feature into replica n&7
        float* s1l = Al;
        float* s2l = Bl;
#pragma unroll
        for (int m = 0; m < 7; m++) {
#pragma unroll
            for (int r = 0; r < 4; r++) {
                const int row = m * 16 + 4 * lgrp + r;
                if (row < 100) {
                    int v = row;
                    if (v >= 75) v -= 75; else if (v >= 50) v -= 50; else if (v >= 25) v -= 25;
                    __hip_atomic_fetch_add(&s1l[v * 66 + dcol], s1r[m][r],
                                           __ATOMIC_RELAXED, __HIP_MEMORY_SCOPE_WORKGROUP);
                    __hip_atomic_fetch_add(&s2l[v * 66 + dcol], s2r[m][r],
                                           __ATOMIC_RELAXED, __HIP_MEMORY_SCOPE_WORKGROUP);
                }
            }
        }
        __syncthreads();
        float* g1 = wsmut + WS_S1 + (n & 7) * 1600;
        float* g2 = wsmut + WS_S2 + (n & 7) * 1600;
        for (int f = tid; f < 1600; f += 256) {
            const int v = f >> 6, d = f & 63;
            atomicAdd(&g1[f], s1l[v * 66 + d]);
            atomicAdd(&g2[f], s2l[v * 66 + d]);
        }
    }
}

extern "C" void kernel_launch(void* const* d_in, const int* in_sizes, int n_in,
                              void* d_out, int out_size, void* d_ws, size_t ws_size,
                              hipStream_t stream) {
    const float* x0    = (const float*)d_in[0];
    const float* fc1_w = (const float*)d_in[1];
    const float* fc1_b = (const float*)d_in[2];
    const float* fc2_w = (const float*)d_in[3];
    const float* fc2_b = (const float*)d_in[4];
    const float* lw    = (const float*)d_in[5];
    const float* lb    = (const float*)d_in[6];
    const float* fmask = (const float*)d_in[7];
    const float* gamma = (const float*)d_in[8];
    const float* beta  = (const float*)d_in[9];
    const int* epoch   = (const int*)d_in[12];
    float* ws  = (float*)d_ws;
    float* out = (float*)d_out;
    const unsigned short* wtb = (const unsigned short*)(ws + WS_WTB);

    k_pool<<<NN * CC, 256, 0, stream>>>(x0, ws + WS_POOLED);
    k_gate<<<1, 256, 0, stream>>>(fc1_w, fc1_b, fc2_w, fc2_b, lb, fmask, epoch, ws);
    k_wfuse<<<NN, 256, 0, stream>>>(lw, ws);
    hipMemsetAsync((char*)d_ws + WS_S1 * sizeof(float), 0, 25600 * sizeof(float), stream);

    dim3 g2(16, 64);
    k_main<0><<<g2, 256, 0, stream>>>(x0, wtb, ws, ws, out);
    k_finalize<<<7, 256, 0, stream>>>(gamma, beta, ws);
    k_main<1><<<g2, 256, 0, stream>>>(x0, wtb, ws, ws, out);
}